// Round 22
// baseline (61.570 us; speedup 1.0000x reference)
//
#include <hip/hip_runtime.h>
#include <hip/hip_bf16.h>

// Problem constants
#define NB   4      // batch
#define CCH  3      // channels
#define HW   320    // height == width
#define KS   5      // kernel/stride
#define LP   4096   // patches per batch (64*64)
#define KD   75     // c*k*k
#define NCH  12     // 16B chunks per patch row (96 bf16 = 12 x 8)

typedef __attribute__((ext_vector_type(4))) float f32x4;
typedef __attribute__((ext_vector_type(8))) short bf16x8;

__device__ __forceinline__ ushort f2bf(float v) {
    __hip_bfloat16 h = __float2bfloat16(v);
    return __builtin_bit_cast(ushort, h);
}

// Kernel 1 (FUSED patch+norm): one thread per patch row. Converts the row to
// the fragment-blocked bf16 layout p2[b][chunk][row] (16B per chunk, chunks
// 10,11 zero) AND accumulates the fp32 sumsq in-flight. Block max -> plain
// store to blockmax[b*16+bx].
__global__ __launch_bounds__(256) void patchnorm_kernel(const float* __restrict__ x,
                                                        ushort* __restrict__ p2,
                                                        float* __restrict__ blockmax) {
    int tid = threadIdx.x;
    int r   = blockIdx.x * 256 + tid;    // patch row 0..4095
    int b   = blockIdx.y;
    int ph = r >> 6, pw = r & 63;
    const float* xb = x + (size_t)b * (CCH * HW * HW) + (size_t)(ph * KS) * HW + pw * KS;
    ushort* pbase = p2 + (size_t)b * NCH * LP * 8 + (size_t)r * 8;

    float ss = 0.f;
    #pragma unroll
    for (int c = 0; c < 10; ++c) {
        bf16x8 v = {};
        #pragma unroll
        for (int j = 0; j < 8; ++j) {
            int k = c * 8 + j;
            if (k < KD) {
                int ch = k / 25, rem = k % 25;
                int ki = rem / 5, kj = rem % 5;
                float f = xb[(size_t)(ch * HW + ki) * HW + kj];
                ss = fmaf(f, f, ss);
                v[j] = (short)f2bf(f);
            }
        }
        *(bf16x8*)&pbase[(size_t)c * LP * 8] = v;
    }
    bf16x8 z = {};
    *(bf16x8*)&pbase[(size_t)10 * LP * 8] = z;
    *(bf16x8*)&pbase[(size_t)11 * LP * 8] = z;

    for (int off = 32; off; off >>= 1) ss = fmaxf(ss, __shfl_xor(ss, off, 64));
    __shared__ float sm[4];
    if ((tid & 63) == 0) sm[tid >> 6] = ss;
    __syncthreads();
    if (tid == 0)
        blockmax[b * 16 + blockIdx.x] =
            fmaxf(fmaxf(sm[0], sm[1]), fmaxf(sm[2], sm[3]));
}

// Kernel 2: C = sigmoid((P P^T)/sqrt(max)), 256-col x 64-row OUTPUT tile per
// block (symmetric-transpose trick, bit-identical). Flat 1D grid, XCD-aware
// remap (round 20, -2.7us): block's XCD = bid & 7; each XCD owns a CONTIGUOUS
// range of 8 j-bands -> compact per-XCD write window. ti sweeps fastest.
// NEW vs round 20 (single variable): stores NONTEMPORAL. With the write
// window compact per-XCD, NT's role is L2 CAPACITY: the 256MB stream no
// longer write-allocates in L2, so p2 (3.15MB) stays fully L2-resident and
// all k-loop fragment reads (384MB aggregate) are L2 hits; the compact
// address pattern still reaches DRAM via the XCD's TCC.
// Everything else identical: direct-from-p2 fragments, blockmax fold,
// hoisted sigmoid (exp+rcpf), 32KB 2-phase XOR-swizzled restage,
// 1024B-aligned 1024B store runs, __launch_bounds__(256,4).
__global__ __launch_bounds__(256, 4) void gemm_kernel(const ushort* __restrict__ p2,
                                                      const float* __restrict__ blockmax,
                                                      float* __restrict__ out) {
    __shared__ float W[32][256];       // 32 KB restage buffer

    int bid = blockIdx.x;
    int xcd = bid & 7;
    int r_  = bid >> 3;                // 0..511 per-XCD sequence
    int ti  = r_ & 15;                 // fast: sweeps i-tiles
    int tjl = (r_ >> 4) & 7;           // j-band within this XCD's range
    int b   = r_ >> 7;                 // slow: batch
    int tj  = xcd * 8 + tjl;           // XCD owns contiguous j-bands

    int tid = threadIdx.x;
    int lane = tid & 63;
    int w    = tid >> 6;
    int lrow = lane & 15;
    int lch  = lane >> 4;

    const ushort* pb = p2 + (size_t)b * NCH * LP * 8;
    int i0 = ti * 256 + w * 64;         // this wave's i-rows (A side, out cols)
    int j0 = tj * 64;                   // block's j-rows (B side, out rows)

    f32x4 acc[4][4] = {};
    #pragma unroll
    for (int ks = 0; ks < 3; ++ks) {
        const ushort* pk = pb + (size_t)(ks * 4 + lch) * LP * 8;  // chunk plane
        bf16x8 af[4], bfr[4];
        #pragma unroll
        for (int m = 0; m < 4; ++m)
            af[m] = *(const bf16x8*)&pk[(size_t)(i0 + m * 16 + lrow) * 8];
        #pragma unroll
        for (int n = 0; n < 4; ++n)
            bfr[n] = *(const bf16x8*)&pk[(size_t)(j0 + n * 16 + lrow) * 8];
        #pragma unroll
        for (int m = 0; m < 4; ++m)
            #pragma unroll
            for (int n = 0; n < 4; ++n)
                acc[m][n] = __builtin_amdgcn_mfma_f32_16x16x32_bf16(af[m], bfr[n], acc[m][n], 0, 0, 0);
    }

    // fold per-batch max from the 16 block maxima (uniform scalar work)
    float mx = 0.f;
    #pragma unroll
    for (int i = 0; i < 16; ++i) mx = fmaxf(mx, blockmax[b * 16 + i]);
    float inv = 1.0f / sqrtf(mx);

    // sigmoid in place on acc: all trans-pipe work done before any barrier
    #pragma unroll
    for (int m = 0; m < 4; ++m)
        #pragma unroll
        for (int n = 0; n < 4; ++n)
            #pragma unroll
            for (int r = 0; r < 4; ++r)
                acc[m][n][r] = __builtin_amdgcn_rcpf(1.0f + __expf(-acc[m][n][r] * inv));

    float* ob = out + (size_t)b * LP * LP;

    // D frag (m,n): out row j = j0 + n*16 + (lane&15); out col i = i0' + m*16
    // + lch*4 + reg. Two phases, 32 j-rows each; barriered phases move data only.
    #pragma unroll
    for (int h = 0; h < 2; ++h) {
        if (h) __syncthreads();         // WAR: previous phase fully read
        #pragma unroll
        for (int np = 0; np < 2; ++np) {
            int n  = h * 2 + np;
            int jr = np * 16 + lrow;               // row 0..31 within phase
            #pragma unroll
            for (int m = 0; m < 4; ++m) {
                // logical 16B slot = w*16 + m*4 + lch; XOR low bits with jr
                int sl = w * 16 + (((m * 4 + lch) ^ (jr & 7)) & 15);
                *(f32x4*)&W[jr][sl * 4] = acc[m][n];
            }
        }
        __syncthreads();
        // each wave stores 8 rows; one instruction = 64 lanes x 16B = 1024B
        // contiguous, 1024B-aligned (row base = multiple of 16KB + ti*1024B)
        #pragma unroll
        for (int r8 = 0; r8 < 8; ++r8) {
            int row = w * 8 + r8;                  // 0..31
            f32x4 v = *(const f32x4*)&W[row][(lane ^ (row & 7)) * 4];
            __builtin_nontemporal_store(v,
                (f32x4*)&ob[(size_t)(j0 + h * 32 + row) * LP + ti * 256 + lane * 4]);
        }
    }
}

extern "C" void kernel_launch(void* const* d_in, const int* in_sizes, int n_in,
                              void* d_out, int out_size, void* d_ws, size_t ws_size,
                              hipStream_t stream) {
    const float* x = (const float*)d_in[0];
    float* out = (float*)d_out;

    // ws layout: p2 bf16 blocked [NB][12][4096][8] (3.15 MB), blockmax f32[64].
    // Everything written-before-read with plain stores each call.
    ushort* p2 = (ushort*)d_ws;
    float* blockmax = (float*)((char*)d_ws + (size_t)NB * NCH * LP * 16);

    patchnorm_kernel<<<dim3(LP / 256, NB), 256, 0, stream>>>(x, p2, blockmax);
    gemm_kernel<<<4096, 256, 0, stream>>>(p2, blockmax, out);
}

// Round 23
// 58.661 us; speedup vs baseline: 1.0496x; 1.0496x over previous
//
#include <hip/hip_runtime.h>
#include <hip/hip_bf16.h>

// Problem constants
#define NB   4      // batch
#define CCH  3      // channels
#define HW   320    // height == width
#define KS   5      // kernel/stride
#define LP   4096   // patches per batch (64*64)
#define KD   75     // c*k*k
#define NCH  12     // 16B chunks per patch row (96 bf16 = 12 x 8)

typedef __attribute__((ext_vector_type(4))) float f32x4;
typedef __attribute__((ext_vector_type(8))) short bf16x8;

__device__ __forceinline__ ushort f2bf(float v) {
    __hip_bfloat16 h = __float2bfloat16(v);
    return __builtin_bit_cast(ushort, h);
}

// Kernel 1 (FUSED patch+norm): one thread per patch row. Converts the row to
// the fragment-blocked bf16 layout p2[b][chunk][row] (16B per chunk, chunks
// 10,11 zero) AND accumulates the fp32 sumsq in-flight. Block max -> plain
// store to blockmax[b*16+bx].
__global__ __launch_bounds__(256) void patchnorm_kernel(const float* __restrict__ x,
                                                        ushort* __restrict__ p2,
                                                        float* __restrict__ blockmax) {
    int tid = threadIdx.x;
    int r   = blockIdx.x * 256 + tid;    // patch row 0..4095
    int b   = blockIdx.y;
    int ph = r >> 6, pw = r & 63;
    const float* xb = x + (size_t)b * (CCH * HW * HW) + (size_t)(ph * KS) * HW + pw * KS;
    ushort* pbase = p2 + (size_t)b * NCH * LP * 8 + (size_t)r * 8;

    float ss = 0.f;
    #pragma unroll
    for (int c = 0; c < 10; ++c) {
        bf16x8 v = {};
        #pragma unroll
        for (int j = 0; j < 8; ++j) {
            int k = c * 8 + j;
            if (k < KD) {
                int ch = k / 25, rem = k % 25;
                int ki = rem / 5, kj = rem % 5;
                float f = xb[(size_t)(ch * HW + ki) * HW + kj];
                ss = fmaf(f, f, ss);
                v[j] = (short)f2bf(f);
            }
        }
        *(bf16x8*)&pbase[(size_t)c * LP * 8] = v;
    }
    bf16x8 z = {};
    *(bf16x8*)&pbase[(size_t)10 * LP * 8] = z;
    *(bf16x8*)&pbase[(size_t)11 * LP * 8] = z;

    for (int off = 32; off; off >>= 1) ss = fmaxf(ss, __shfl_xor(ss, off, 64));
    __shared__ float sm[4];
    if ((tid & 63) == 0) sm[tid >> 6] = ss;
    __syncthreads();
    if (tid == 0)
        blockmax[b * 16 + blockIdx.x] =
            fmaxf(fmaxf(sm[0], sm[1]), fmaxf(sm[2], sm[3]));
}

// Kernel 2: C = sigmoid((P P^T)/sqrt(max)), 256-col x 64-row OUTPUT tile per
// block (symmetric-transpose trick, bit-identical). Flat 1D grid, XCD-aware
// remap (round 20, -2.7us): block's XCD = bid & 7 (8-XCD round-robin
// dispatch); each XCD owns a CONTIGUOUS range of 8 j-bands -> compact per-XCD
// write window, address-compact dirty evictions. ti sweeps fastest.
// Stores PLAIN write-back (round 22 A/B: NT regressed -2.9us in this regime —
// L2 dirty-eviction batching beats NT write-through for the compact stream).
// Everything else: direct-from-p2 fragments, blockmax fold, hoisted sigmoid
// (exp+rcpf), 32KB 2-phase XOR-swizzled restage, 1024B-aligned 1024B store
// runs (arch max: 64 lanes x 16B), __launch_bounds__(256,4).
__global__ __launch_bounds__(256, 4) void gemm_kernel(const ushort* __restrict__ p2,
                                                      const float* __restrict__ blockmax,
                                                      float* __restrict__ out) {
    __shared__ float W[32][256];       // 32 KB restage buffer

    int bid = blockIdx.x;
    int xcd = bid & 7;
    int r_  = bid >> 3;                // 0..511 per-XCD sequence
    int ti  = r_ & 15;                 // fast: sweeps i-tiles
    int tjl = (r_ >> 4) & 7;           // j-band within this XCD's range
    int b   = r_ >> 7;                 // slow: batch
    int tj  = xcd * 8 + tjl;           // XCD owns contiguous j-bands

    int tid = threadIdx.x;
    int lane = tid & 63;
    int w    = tid >> 6;
    int lrow = lane & 15;
    int lch  = lane >> 4;

    const ushort* pb = p2 + (size_t)b * NCH * LP * 8;
    int i0 = ti * 256 + w * 64;         // this wave's i-rows (A side, out cols)
    int j0 = tj * 64;                   // block's j-rows (B side, out rows)

    f32x4 acc[4][4] = {};
    #pragma unroll
    for (int ks = 0; ks < 3; ++ks) {
        const ushort* pk = pb + (size_t)(ks * 4 + lch) * LP * 8;  // chunk plane
        bf16x8 af[4], bfr[4];
        #pragma unroll
        for (int m = 0; m < 4; ++m)
            af[m] = *(const bf16x8*)&pk[(size_t)(i0 + m * 16 + lrow) * 8];
        #pragma unroll
        for (int n = 0; n < 4; ++n)
            bfr[n] = *(const bf16x8*)&pk[(size_t)(j0 + n * 16 + lrow) * 8];
        #pragma unroll
        for (int m = 0; m < 4; ++m)
            #pragma unroll
            for (int n = 0; n < 4; ++n)
                acc[m][n] = __builtin_amdgcn_mfma_f32_16x16x32_bf16(af[m], bfr[n], acc[m][n], 0, 0, 0);
    }

    // fold per-batch max from the 16 block maxima (uniform scalar work)
    float mx = 0.f;
    #pragma unroll
    for (int i = 0; i < 16; ++i) mx = fmaxf(mx, blockmax[b * 16 + i]);
    float inv = 1.0f / sqrtf(mx);

    // sigmoid in place on acc: all trans-pipe work done before any barrier
    #pragma unroll
    for (int m = 0; m < 4; ++m)
        #pragma unroll
        for (int n = 0; n < 4; ++n)
            #pragma unroll
            for (int r = 0; r < 4; ++r)
                acc[m][n][r] = __builtin_amdgcn_rcpf(1.0f + __expf(-acc[m][n][r] * inv));

    float* ob = out + (size_t)b * LP * LP;

    // D frag (m,n): out row j = j0 + n*16 + (lane&15); out col i = i0' + m*16
    // + lch*4 + reg. Two phases, 32 j-rows each; barriered phases move data only.
    #pragma unroll
    for (int h = 0; h < 2; ++h) {
        if (h) __syncthreads();         // WAR: previous phase fully read
        #pragma unroll
        for (int np = 0; np < 2; ++np) {
            int n  = h * 2 + np;
            int jr = np * 16 + lrow;               // row 0..31 within phase
            #pragma unroll
            for (int m = 0; m < 4; ++m) {
                // logical 16B slot = w*16 + m*4 + lch; XOR low bits with jr
                int sl = w * 16 + (((m * 4 + lch) ^ (jr & 7)) & 15);
                *(f32x4*)&W[jr][sl * 4] = acc[m][n];
            }
        }
        __syncthreads();
        // each wave stores 8 rows; one instruction = 64 lanes x 16B = 1024B
        // contiguous, 1024B-aligned (row base = multiple of 16KB + ti*1024B)
        #pragma unroll
        for (int r8 = 0; r8 < 8; ++r8) {
            int row = w * 8 + r8;                  // 0..31
            f32x4 v = *(const f32x4*)&W[row][(lane ^ (row & 7)) * 4];
            *(f32x4*)&ob[(size_t)(j0 + h * 32 + row) * LP + ti * 256 + lane * 4] = v;
        }
    }
}

extern "C" void kernel_launch(void* const* d_in, const int* in_sizes, int n_in,
                              void* d_out, int out_size, void* d_ws, size_t ws_size,
                              hipStream_t stream) {
    const float* x = (const float*)d_in[0];
    float* out = (float*)d_out;

    // ws layout: p2 bf16 blocked [NB][12][4096][8] (3.15 MB), blockmax f32[64].
    // Everything written-before-read with plain stores each call.
    ushort* p2 = (ushort*)d_ws;
    float* blockmax = (float*)((char*)d_ws + (size_t)NB * NCH * LP * 16);

    patchnorm_kernel<<<dim3(LP / 256, NB), 256, 0, stream>>>(x, p2, blockmax);
    gemm_kernel<<<4096, 256, 0, stream>>>(p2, blockmax, out);
}